// Round 9
// baseline (892.976 us; speedup 1.0000x reference)
//
#include <hip/hip_runtime.h>
#include <cfloat>
#include <cstdint>

// ---------------- problem constants ----------------
#define B_BATCH 32
#define D_DIM   256
#define HW      1024
#define N_POS   32768
#define K_CODES 1024
#define DECAY_F   0.99f
#define ONE_M_DECAY 0.01f
#define EPS_F   1e-5f
#define GRID_P  1024          // persistent grid: exactly 4 blocks/CU x 256 CUs

// ---------------- output layout (floats) ----------------
#define OUT_Q    0                         // 8388608  quantized_st (B,C,H,W)
#define OUT_LOSS 8388608                   // 1
#define OUT_PERP 8388609                   // 1
#define OUT_CB   8388610                   // 262144   new_codebook
#define OUT_NCS  8650754                   // 1024     new_cluster_size
#define OUT_EDW  8651778                   // 262144   new_ema_dw (dw scratch first)

// OUT_Q region doubles as z bf16 hi/lo scratch (exactly 33,554,432 bytes):
// P0 writes zhi (16 MB) + zlo (16 MB); P1 argmin + P5 dw read them;
// P6 tail overwrites the region with the real output.

// ---------------- workspace layout (bytes) ----------------
#define WS_COUNTS  0          // 1024*4
#define WS_ZNORM   4096       // 4
#define WS_BSUM    4100       // 4
#define WS_NTOT    4104       // 4
#define WS_BAR     4108       // 6*4 barrier counters
#define WS_MEMSET  4132       // bytes zeroed at launch
#define WS_CBNORM  5376       // 1024*4
#define WS_OFFS    9472       // 1024*4 (int)
#define WS_CURSOR  13568      // 1024*4 (int)
#define WS_IDX     17664      // 32768*4 (int)
#define WS_SORTED  148736     // 32768*4 (int)
#define WS_CBHI    279808     // 262144*2
#define WS_CBLO    804096     // 262144*2
#define WS_PART    1328384    // 32768*8*8 (u64 partial keys)
#define WS_SCODE   3425536    // 32768*4 (int)
#define WS_TOTAL   3556608

typedef short s16x8 __attribute__((ext_vector_type(8)));
typedef float f32x4 __attribute__((ext_vector_type(4)));
typedef unsigned long long u64;

__device__ __forceinline__ ushort f2bf_rne(float x) {
    uint u = __float_as_uint(x);
    uint r = (u + 0x7FFF + ((u >> 16) & 1)) >> 16;
    return (ushort)r;
}
__device__ __forceinline__ float bf2f(ushort h) {
    return __uint_as_float(((uint)h) << 16);
}

// async global->LDS, 16 B per lane; LDS dst = wave-uniform base + lane*16
__device__ __forceinline__ void gload16(const void* g, void* l) {
    __builtin_amdgcn_global_load_lds(
        (const __attribute__((address_space(1))) unsigned*)(uintptr_t)g,
        (__attribute__((address_space(3))) unsigned*)(uintptr_t)l, 16, 0, 0);
}

// grid barrier: all GRID_P blocks co-resident (exact-capacity launch).
// Release/acquire fence pattern validated by R8's grid-last combine.
__device__ __forceinline__ void grid_barrier(int* ctr) {
    __syncthreads();
    if (threadIdx.x == 0) {
        __threadfence();                   // release prior writes device-wide
        atomicAdd(ctr, 1);
        while (atomicAdd(ctr, 0) < GRID_P) __builtin_amdgcn_s_sleep(8);
        __threadfence();                   // acquire other blocks' writes
    }
    __syncthreads();
}

// ============================================================
__global__ __launch_bounds__(256, 4) void mega_kernel(
        const float* __restrict__ z, const float* __restrict__ cb,
        const float* __restrict__ ema_cs, const float* __restrict__ ema_dw,
        ushort* __restrict__ zhi, ushort* __restrict__ zlo,
        ushort* __restrict__ cbhi, ushort* __restrict__ cblo,
        float* __restrict__ cbnorm, float* __restrict__ znorm_acc,
        u64* __restrict__ partial, int* __restrict__ idx,
        float* __restrict__ counts, float* __restrict__ bsum_acc,
        float* __restrict__ out_ncs, float* __restrict__ out_perp,
        float* __restrict__ out_loss, float* __restrict__ ntot_ws,
        int* __restrict__ offsets, int* __restrict__ cursor,
        int* __restrict__ sorted, int* __restrict__ scode,
        float* __restrict__ dw, float* __restrict__ out_cb,
        float* __restrict__ outq, int* __restrict__ bars) {

    __shared__ __align__(16) ushort SMEM[17408];   // 34816 B, aliased per phase

    const int tid = threadIdx.x;
    const int blk = blockIdx.x;

    // ================= P0: prep (768 units) =================
    if (blk < 768) {
        if (blk >= 512) {               // codebook -> bf16 hi/lo + norms
            int wave = tid >> 6;
            int lane = tid & 63;
            int k = (blk - 512) * 4 + wave;
            float4 v = *(const float4*)&cb[(size_t)k * D_DIM + lane * 4];
            ushort4 h, l;
            h.x = f2bf_rne(v.x); l.x = f2bf_rne(v.x - bf2f(h.x));
            h.y = f2bf_rne(v.y); l.y = f2bf_rne(v.y - bf2f(h.y));
            h.z = f2bf_rne(v.z); l.z = f2bf_rne(v.z - bf2f(h.z));
            h.w = f2bf_rne(v.w); l.w = f2bf_rne(v.w - bf2f(h.w));
            *(ushort4*)&cbhi[(size_t)k * D_DIM + lane * 4] = h;
            *(ushort4*)&cblo[(size_t)k * D_DIM + lane * 4] = l;
            float s = v.x * v.x + v.y * v.y + v.z * v.z + v.w * v.w;
            #pragma unroll
            for (int off = 32; off >= 1; off >>= 1) s += __shfl_xor(s, off);
            if (lane == 0) cbnorm[k] = s;
        } else {                        // z transpose + bf16 split + ||z||^2
            float* Zs  = (float*)SMEM;                        // [32][65]
            float* red = (float*)((char*)SMEM + 8320);        // 256 f
            const int n0  = blk * 64;
            const int b   = n0 >> 10;
            const int hw0 = n0 & 1023;
            const float* zb = z + (size_t)b * (D_DIM * HW) + hw0;
            const int zn = tid & 63;
            const int zdb = (tid >> 6) * 8;
            const int n  = tid >> 2;
            const int dq = tid & 3;
            float zsum = 0.f;
            for (int d0 = 0; d0 < D_DIM; d0 += 32) {
                __syncthreads();
                #pragma unroll
                for (int j = 0; j < 8; ++j)
                    Zs[(zdb + j) * 65 + zn] = zb[(size_t)(d0 + zdb + j) * HW + zn];
                __syncthreads();
                s16x8 hv, lv;
                #pragma unroll
                for (int j = 0; j < 8; ++j) {
                    float f = Zs[(dq * 8 + j) * 65 + n];
                    zsum += f * f;
                    ushort hb = f2bf_rne(f);
                    ushort lb = f2bf_rne(f - bf2f(hb));
                    hv[j] = (short)hb;
                    lv[j] = (short)lb;
                }
                *(s16x8*)&zhi[(size_t)(n0 + n) * D_DIM + d0 + dq * 8] = hv;
                *(s16x8*)&zlo[(size_t)(n0 + n) * D_DIM + d0 + dq * 8] = lv;
            }
            red[tid] = zsum;
            __syncthreads();
            for (int s2 = 128; s2 >= 1; s2 >>= 1) {
                if (tid < s2) red[tid] += red[tid + s2];
                __syncthreads();
            }
            if (tid == 0) atomicAdd(znorm_acc, red[0]);
        }
    }
    grid_barrier(&bars[0]);

    // ================= P1: argmin GEMM (2048 units, 2 per block) ============
    {
        ushort* lds   = SMEM;                           // 16384 ushorts
        u64*    kred2 = (u64*)&SMEM[16384];             // 128*2 u64
        const int wave = tid >> 6;
        const int lane = tid & 63;
        const int col  = lane & 15;
        const int lg   = lane >> 4;
        const int ch = wave & 1;
        const int ph = wave >> 1;
        const int r0  = tid >> 2;
        const int dch = (tid & 3) ^ ((r0 >> 1) & 3);
        const int ldsw = wave * 512;
        const int swz = (lg ^ ((col >> 1) & 3)) * 8;
        const int soffA = (ch * 64 + col) * 32 + swz;
        const int soffB = (ph * 64 + col) * 32 + swz;

        for (int u = blk; u < 2048; u += GRID_P) {
            const int mt = (u >> 3) & 7;                 // code tile
            const int pt = (u & 7) | ((u >> 6) << 3);    // position tile
            const size_t eA0 = (size_t)(mt * 128 + r0) * D_DIM + dch * 8;
            const size_t eB0 = (size_t)(pt * 128 + r0) * D_DIM + dch * 8;

            f32x4 acc[4][4];
            #pragma unroll
            for (int mi = 0; mi < 4; ++mi)
                #pragma unroll
                for (int ni = 0; ni < 4; ++ni) acc[mi][ni] = {0.f, 0.f, 0.f, 0.f};

            for (int s8 = 0; s8 < 8; ++s8) {
                const int d0 = s8 * 32;
                __syncthreads();
                gload16(cbhi + eA0 + d0,            &lds[0     + ldsw]);
                gload16(cbhi + eA0 + 64 * 256 + d0, &lds[2048  + ldsw]);
                gload16(cblo + eA0 + d0,            &lds[4096  + ldsw]);
                gload16(cblo + eA0 + 64 * 256 + d0, &lds[6144  + ldsw]);
                gload16(zhi  + eB0 + d0,            &lds[8192  + ldsw]);
                gload16(zhi  + eB0 + 64 * 256 + d0, &lds[10240 + ldsw]);
                gload16(zlo  + eB0 + d0,            &lds[12288 + ldsw]);
                gload16(zlo  + eB0 + 64 * 256 + d0, &lds[14336 + ldsw]);
                __syncthreads();

                s16x8 ah[4], al[4], bh[4], bl[4];
                #pragma unroll
                for (int mi = 0; mi < 4; ++mi) {
                    int so = soffA + mi * 512;
                    ah[mi] = *(const s16x8*)&lds[so];
                    al[mi] = *(const s16x8*)&lds[4096 + so];
                }
                #pragma unroll
                for (int ni = 0; ni < 4; ++ni) {
                    int so = soffB + ni * 512;
                    bh[ni] = *(const s16x8*)&lds[8192 + so];
                    bl[ni] = *(const s16x8*)&lds[12288 + so];
                }
                #pragma unroll
                for (int mi = 0; mi < 4; ++mi)
                    #pragma unroll
                    for (int ni = 0; ni < 4; ++ni) {
                        acc[mi][ni] = __builtin_amdgcn_mfma_f32_16x16x32_bf16(ah[mi], bh[ni], acc[mi][ni], 0, 0, 0);
                        acc[mi][ni] = __builtin_amdgcn_mfma_f32_16x16x32_bf16(ah[mi], bl[ni], acc[mi][ni], 0, 0, 0);
                        acc[mi][ni] = __builtin_amdgcn_mfma_f32_16x16x32_bf16(al[mi], bh[ni], acc[mi][ni], 0, 0, 0);
                    }
            }

            const int kbase = mt * 128 + ch * 64;
            u64 best[4] = {~0ull, ~0ull, ~0ull, ~0ull};
            #pragma unroll
            for (int mi = 0; mi < 4; ++mi) {
                float4 cn = *(const float4*)&cbnorm[kbase + mi * 16 + lg * 4];
                const float* cnp = (const float*)&cn;
                #pragma unroll
                for (int ni = 0; ni < 4; ++ni) {
                    #pragma unroll
                    for (int r = 0; r < 4; ++r) {
                        float dist = cnp[r] - 2.f * acc[mi][ni][r];
                        uint ub = __float_as_uint(dist);
                        ub = ub ^ (uint)(((int)ub >> 31) | 0x80000000);
                        u64 key = ((u64)ub << 32) | (uint)(kbase + mi * 16 + lg * 4 + r);
                        if (key < best[ni]) best[ni] = key;
                    }
                }
            }
            #pragma unroll
            for (int ni = 0; ni < 4; ++ni) {
                u64 o = __shfl_xor(best[ni], 16); if (o < best[ni]) best[ni] = o;
                o = __shfl_xor(best[ni], 32); if (o < best[ni]) best[ni] = o;
            }
            if (lane < 16) {
                #pragma unroll
                for (int ni = 0; ni < 4; ++ni)
                    kred2[(ph * 64 + ni * 16 + lane) * 2 + ch] = best[ni];
            }
            __syncthreads();
            if (tid < 128) {
                u64 a = kred2[tid * 2], b = kred2[tid * 2 + 1];
                partial[(size_t)(pt * 128 + tid) * 8 + mt] = a < b ? a : b;
            }
        }
    }
    grid_barrier(&bars[1]);

    // ================= P2: combine (128 units) =================
    if (blk < 128) {
        int*   hist = (int*)SMEM;                          // 1024 ints
        float* redf = (float*)((char*)SMEM + 4096);        // 256 f
        for (int j = tid; j < 1024; j += 256) hist[j] = 0;
        __syncthreads();
        int n = blk * 256 + tid;
        const u64* p = partial + (size_t)n * 8;
        u64 m = p[0];
        #pragma unroll
        for (int j = 1; j < 8; ++j) { u64 v = p[j]; if (v < m) m = v; }
        int k = (int)(m & 1023u);
        idx[n] = k;
        atomicAdd(&hist[k], 1);
        uint ub = (uint)(m >> 32);
        uint uu = (ub & 0x80000000u) ? (ub ^ 0x80000000u) : ~ub;
        redf[tid] = __uint_as_float(uu);
        __syncthreads();
        for (int s2 = 128; s2 >= 1; s2 >>= 1) {
            if (tid < s2) redf[tid] += redf[tid + s2];
            __syncthreads();
        }
        if (tid == 0) atomicAdd(bsum_acc, redf[0]);
        for (int j = tid; j < 1024; j += 256) {
            int c = hist[j];
            if (c) atomicAdd(&counts[j], (float)c);
        }
    }
    grid_barrier(&bars[2]);

    // ================= P3: stats/scan (block 0) =================
    if (blk == 0) {
        int*   si = (int*)SMEM;                            // 256 ints
        float* s1 = (float*)((char*)SMEM + 1024);          // 256 f
        float* s2 = (float*)((char*)SMEM + 2048);          // 256 f
        const int base = tid * 4;
        int c4[4];
        int ssum = 0;
        float n1 = 0.f, n2 = 0.f;
        #pragma unroll
        for (int j = 0; j < 4; ++j) {
            float cnt = counts[base + j];
            int ci = (int)cnt;
            c4[j] = ci;
            ssum += ci;
            float ncs = ema_cs[base + j] * DECAY_F + ONE_M_DECAY * cnt;
            out_ncs[base + j] = ncs;
            n1 += ncs;
            float pr = cnt / (float)N_POS;
            n2 += pr * logf(pr + 1e-10f);
        }
        si[tid] = ssum;
        __syncthreads();
        for (int off = 1; off < 256; off <<= 1) {
            int v = (tid >= off) ? si[tid - off] : 0;
            __syncthreads();
            si[tid] += v;
            __syncthreads();
        }
        int run = si[tid] - ssum;
        #pragma unroll
        for (int j = 0; j < 4; ++j) {
            offsets[base + j] = run;
            cursor[base + j] = run;
            run += c4[j];
        }
        s1[tid] = n1;
        s2[tid] = n2;
        __syncthreads();
        for (int st = 128; st >= 1; st >>= 1) {
            if (tid < st) { s1[tid] += s1[tid + st]; s2[tid] += s2[tid + st]; }
            __syncthreads();
        }
        if (tid == 0) {
            ntot_ws[0] = s1[0];
            out_perp[0] = expf(-s2[0]);
            out_loss[0] = 0.25f * (znorm_acc[0] + bsum_acc[0]) / 8388608.0f;
        }
    }
    grid_barrier(&bars[3]);

    // ================= P4: scatter (128 units) + zero dw =================
    if (blk < 128) {
        int* hist   = (int*)SMEM;                          // 1024 ints
        int* base_s = (int*)((char*)SMEM + 4096);          // 1024 ints
        {
            float4 z4 = {0.f, 0.f, 0.f, 0.f};
            size_t e = ((size_t)blk * 256 + tid) * 8;
            *(float4*)&dw[e] = z4;
            *(float4*)&dw[e + 4] = z4;
        }
        for (int j = tid; j < 1024; j += 256) hist[j] = 0;
        __syncthreads();
        int n = blk * 256 + tid;
        int k = idx[n];
        atomicAdd(&hist[k], 1);
        __syncthreads();
        for (int j = tid; j < 1024; j += 256) {
            int c = hist[j];
            if (c) base_s[j] = atomicAdd(&cursor[j], c);
            hist[j] = 0;
        }
        __syncthreads();
        int rank = atomicAdd(&hist[k], 1);
        int pos = base_s[k] + rank;
        sorted[pos] = n;
        scode[pos] = k;
    }
    grid_barrier(&bars[4]);

    // ================= P5: dw segmented sum (512 units) =================
    if (blk < 512) {
        int* sid = (int*)SMEM;                             // 64 ints
        int* sk  = (int*)((char*)SMEM + 256);              // 64 ints
        const int p0 = blk * 64;
        if (tid < 64) {
            sid[tid] = sorted[p0 + tid];
            sk[tid]  = scode[p0 + tid];
        }
        __syncthreads();
        float acc = 0.f;
        int runstart = 0;
        #pragma unroll 4
        for (int i = 0; i < 64; ++i) {
            int id = sid[i];
            float zv = bf2f(zhi[(size_t)id * D_DIM + tid]) + bf2f(zlo[(size_t)id * D_DIM + tid]);
            acc += zv;
            bool end = (i == 63) || (sk[i + 1] != sk[i]);
            if (end) {
                int k = sk[i];
                int off = offsets[k];
                int cnt = (int)counts[k];
                if (p0 + runstart == off && p0 + i == off + cnt - 1)
                    dw[(size_t)k * D_DIM + tid] = acc;
                else
                    atomicAdd(&dw[(size_t)k * D_DIM + tid], acc);
                acc = 0.f;
                runstart = i + 1;
            }
        }
    }
    grid_barrier(&bars[5]);

    // ================= P6: tail (1536 units) =================
    for (int u = blk; u < 1536; u += GRID_P) {
        if (u < 1024) {      // finalize row u
            int k = u;
            float ncs = out_ncs[k];
            float nt = ntot_ws[0];
            float csz = (ncs + EPS_F) / (nt + (float)K_CODES * EPS_F) * nt;
            size_t e = (size_t)k * D_DIM + tid;
            float ed = ema_dw[e] * DECAY_F + ONE_M_DECAY * dw[e];
            dw[e] = ed;                       // new_ema_dw in place
            out_cb[e] = ed / csz;
        } else {             // fuse: outq = cb[idx]
            float* Qs  = (float*)SMEM;                     // [32][65]
            int*  kidx = (int*)((char*)SMEM + 8320);       // 64 ints
            const int n0  = (u - 1024) * 64;
            const int b   = n0 >> 10;
            const int hw0 = n0 & 1023;
            float* ob = outq + (size_t)b * (D_DIM * HW) + hw0;
            __syncthreads();
            if (tid < 64) kidx[tid] = idx[n0 + tid];
            for (int d0 = 0; d0 < D_DIM; d0 += 32) {
                __syncthreads();
                #pragma unroll
                for (int h = 0; h < 2; ++h) {
                    int s  = tid + 256 * h;
                    int n  = s >> 3;
                    int dq = s & 7;
                    int k  = kidx[n];
                    float4 q = *(const float4*)&cb[(size_t)k * D_DIM + d0 + dq * 4];
                    Qs[(dq * 4 + 0) * 65 + n] = q.x;
                    Qs[(dq * 4 + 1) * 65 + n] = q.y;
                    Qs[(dq * 4 + 2) * 65 + n] = q.z;
                    Qs[(dq * 4 + 3) * 65 + n] = q.w;
                }
                __syncthreads();
                #pragma unroll
                for (int j = 0; j < 8; ++j) {
                    int v = tid + 256 * j;
                    int d = v >> 6;
                    int n = v & 63;
                    ob[(size_t)(d0 + d) * HW + n] = Qs[d * 65 + n];
                }
            }
        }
    }
}

// ============================================================
extern "C" void kernel_launch(void* const* d_in, const int* in_sizes, int n_in,
                              void* d_out, int out_size, void* d_ws, size_t ws_size,
                              hipStream_t stream) {
    const float* z       = (const float*)d_in[0];
    const float* cb      = (const float*)d_in[1];
    const float* ema_cs  = (const float*)d_in[2];
    const float* ema_dw  = (const float*)d_in[3];
    float* out = (float*)d_out;

    char* ws = (char*)d_ws;
    float* ws_counts = (float*)(ws + WS_COUNTS);
    float* ws_znorm  = (float*)(ws + WS_ZNORM);
    float* ws_bsum   = (float*)(ws + WS_BSUM);
    float* ws_ntot   = (float*)(ws + WS_NTOT);
    int*   ws_bars   = (int*)(ws + WS_BAR);
    float* ws_cbnorm = (float*)(ws + WS_CBNORM);
    int*   ws_offs   = (int*)(ws + WS_OFFS);
    int*   ws_cursor = (int*)(ws + WS_CURSOR);
    int*   ws_idx    = (int*)(ws + WS_IDX);
    int*   ws_sorted = (int*)(ws + WS_SORTED);
    ushort* ws_cbhi  = (ushort*)(ws + WS_CBHI);
    ushort* ws_cblo  = (ushort*)(ws + WS_CBLO);
    u64*   ws_part   = (u64*)(ws + WS_PART);
    int*   ws_scode  = (int*)(ws + WS_SCODE);

    // zhi/zlo scratch lives in the OUT_Q region (exactly 32 MB)
    ushort* zhi = (ushort*)out;
    ushort* zlo = zhi + 8388608;

    hipMemsetAsync(d_ws, 0, WS_MEMSET, stream);

    mega_kernel<<<GRID_P, 256, 0, stream>>>(
        z, cb, ema_cs, ema_dw,
        zhi, zlo, ws_cbhi, ws_cblo,
        ws_cbnorm, ws_znorm, ws_part, ws_idx,
        ws_counts, ws_bsum,
        out + OUT_NCS, out + OUT_PERP, out + OUT_LOSS, ws_ntot,
        ws_offs, ws_cursor, ws_sorted, ws_scode,
        out + OUT_EDW, out + OUT_CB, out + OUT_Q, ws_bars);
}